// Round 13
// baseline (520.936 us; speedup 1.0000x reference)
//
#include <hip/hip_runtime.h>
#include <cstdint>
#include <cstddef>

// EEGFormer block on MI355X. N=32768 tokens, L=512, H=8 heads of D=64, C=256 region.
#define NTOK 32768
#define LDIM 512
#define HN 8
#define HD 64
#define CC 256
#define FFD 2048

typedef __bf16 bf16x8 __attribute__((ext_vector_type(8)));
typedef float f32x4 __attribute__((ext_vector_type(4)));
typedef unsigned short u16;
typedef unsigned int u32;

__device__ __forceinline__ u16 f2bf(float f) {
  u32 u = __float_as_uint(f);
  u32 r = (u + 0x7fffu + ((u >> 16) & 1u)) >> 16;  // RNE
  return (u16)r;
}

__device__ __forceinline__ void gload_lds16(const void* g, void* l) {
  __builtin_amdgcn_global_load_lds(
      (__attribute__((address_space(1))) void*)(void*)g,
      (__attribute__((address_space(3))) void*)l, 16, 0, 0);
}

// ---------------- f32 -> bf16 convert (all weights, one launch) ----------------
__global__ void k_convall(const float* __restrict__ Wq, const float* __restrict__ Wk,
                          const float* __restrict__ Wv, const float* __restrict__ Wo,
                          const float* __restrict__ W1, const float* __restrict__ W2,
                          u16* __restrict__ wqkv, u16* __restrict__ wo,
                          u16* __restrict__ w1, u16* __restrict__ w2) {
  const int NW = 262144;            // 512*512
  const int MW = 1048576;           // 2048*512
  const int TOT = 4 * NW + 2 * MW;  // 3145728
  int i = blockIdx.x * blockDim.x + threadIdx.x;
  const int st = gridDim.x * blockDim.x;
  for (; i < TOT; i += st) {
    if (i < NW) wqkv[i] = f2bf(Wq[i]);
    else if (i < 2 * NW) wqkv[i] = f2bf(Wk[i - NW]);
    else if (i < 3 * NW) wqkv[i] = f2bf(Wv[i - 2 * NW]);
    else if (i < 4 * NW) wo[i - 3 * NW] = f2bf(Wo[i - 3 * NW]);
    else if (i < 4 * NW + MW) w1[i - 4 * NW] = f2bf(W1[i - 4 * NW]);
    else w2[i - 4 * NW - MW] = f2bf(W2[i - 4 * NW - MW]);
  }
}

// ---------------- LayerNorm (f32 in -> bf16 out), 1 wave per row ----------------
__global__ __launch_bounds__(256) void k_ln(const float* __restrict__ x,
                                            const float* __restrict__ gam,
                                            const float* __restrict__ bet,
                                            u16* __restrict__ out) {
  const int row = blockIdx.x * 4 + (threadIdx.x >> 6);
  const int lane = threadIdx.x & 63;
  const float4* xr = (const float4*)(x + (size_t)row * LDIM);
  float4 a = xr[lane * 2], b = xr[lane * 2 + 1];
  float s = a.x + a.y + a.z + a.w + b.x + b.y + b.z + b.w;
  float q = a.x * a.x + a.y * a.y + a.z * a.z + a.w * a.w +
            b.x * b.x + b.y * b.y + b.z * b.z + b.w * b.w;
#pragma unroll
  for (int m = 1; m < 64; m <<= 1) { s += __shfl_xor(s, m); q += __shfl_xor(q, m); }
  const float mean = s * (1.f / LDIM);
  const float rs = rsqrtf(q * (1.f / LDIM) - mean * mean + 1e-5f);
  const int c0 = lane * 8;
  const float4* g4 = (const float4*)(gam + c0);
  const float4* b4 = (const float4*)(bet + c0);
  float4 ga = g4[0], gb = g4[1], ba = b4[0], bb = b4[1];
  float vin[8] = {a.x, a.y, a.z, a.w, b.x, b.y, b.z, b.w};
  float vg[8]  = {ga.x, ga.y, ga.z, ga.w, gb.x, gb.y, gb.z, gb.w};
  float vb[8]  = {ba.x, ba.y, ba.z, ba.w, bb.x, bb.y, bb.z, bb.w};
  u16 o[8];
#pragma unroll
  for (int i = 0; i < 8; ++i) o[i] = f2bf((vin[i] - mean) * rs * vg[i] + vb[i]);
  *(bf16x8*)(out + (size_t)row * LDIM + c0) = *(bf16x8*)o;
}

// ---------------- 128x128 GEMM, m97-structure, high residency: C = A[M,K]*Bw[N,K]^T ----------------
// 4 waves (2x2, wave-tile 64x64), SINGLE-buffered 16KB static LDS, 256 threads,
// two __syncthreads per K-tile, compiler-managed waitcnts, NO min-waves clause.
// Rationale (R1-R12 + m97 fit): staged delivery ~6-8 B/cy per RESIDENT block,
// linear in blocks/CU (m97: 3-4 blocks -> 14.3 TB/s; all my 1-2 block configs
// -> 7-8 TB/s). This config: VGPR ~60, LDS 16KB -> 6-8 resident blocks/CU.
// R1 (same shape) was throttled by 8-way ds_read bank conflicts -> fixed here
// by the verified chunk-XOR swizzle (0 conflicts since R3).
// Swizzle: 16B chunk c of row r at slot c^((r>>1)&3), applied on pre-swizzled
// global source AND ds_read (involution; source stays 64B-coalesced).
// bn-major block order: consecutive co-XCD blocks share the A-panel (L2 reuse).
// EPI: 0 bf16 store; 1 +bias+resid(f32)->f32; 2 relu(+bias)->bf16; 3 f32 out += acc+bias

__device__ __forceinline__ void stage_tile32(const u16* __restrict__ Ag,
                                             const u16* __restrict__ Bg, int K, int k0,
                                             u16* __restrict__ SA, u16* __restrict__ SB,
                                             int t) {
#pragma unroll
  for (int i = 0; i < 2; ++i) {
    const int p = i * 256 + t;
    const int r = p >> 2;                          // row 0..127
    const int c = ((p & 3) ^ ((r >> 1) & 3)) << 3; // swizzled 16B chunk -> elem offset
    const int dst = (i * 256 + (t & ~63)) << 3;    // wave-uniform LDS base (elems)
    gload_lds16(Ag + (size_t)r * K + k0 + c, SA + dst);
    gload_lds16(Bg + (size_t)r * K + k0 + c, SB + dst);
  }
}

__device__ __forceinline__ bf16x8 ldsfrag32(const u16* __restrict__ s, int R, int kq) {
  return *(const bf16x8*)(s + R * 32 + ((kq ^ ((R >> 1) & 3)) << 3));
}

template <int EPI>
__global__ __launch_bounds__(256) void k_gemm(const u16* __restrict__ A,
                                              const u16* __restrict__ Bw, int K,
                                              const float* __restrict__ bias,
                                              const float* __restrict__ resid,
                                              void* __restrict__ outp, int ldc,
                                              int bnN) {
  __shared__ u16 SA[128 * 32];
  __shared__ u16 SB[128 * 32];
  const int t = threadIdx.x;
  const int lane = t & 63;
  const int w = t >> 6;
  const int wm = w >> 1, wn = w & 1;  // 2x2 waves, wave tile 64x64
  const int rl = lane & 15;
  const int kq = lane >> 4;  // 16B chunk within 32-K row
  // XCD-chunked block swizzle (grid %8==0); bn-major: consecutive co-XCD
  // sids share bm (the A-panel) and span bn.
  const int nwg = gridDim.x;
  const int cpx = nwg >> 3;
  const int id = blockIdx.x;
  const int sid = (id & 7) * cpx + (id >> 3);
  const int bn = sid % bnN, bm = sid / bnN;

  const u16* Ag = A + (size_t)bm * 128 * K;
  const u16* Bg = Bw + (size_t)bn * 128 * K;

  f32x4 acc[4][4] = {};

  const int NT = K >> 5;
  for (int T = 0; T < NT; ++T) {
    stage_tile32(Ag, Bg, K, T << 5, SA, SB, t);
    __syncthreads();  // drains vmcnt(0): tile published
    bf16x8 a[4], b[4];
#pragma unroll
    for (int f = 0; f < 4; ++f) a[f] = ldsfrag32(SA, wm * 64 + f * 16 + rl, kq);
#pragma unroll
    for (int n = 0; n < 4; ++n) b[n] = ldsfrag32(SB, wn * 64 + n * 16 + rl, kq);
#pragma unroll
    for (int f = 0; f < 4; ++f)
#pragma unroll
      for (int n = 0; n < 4; ++n)
        acc[f][n] = __builtin_amdgcn_mfma_f32_16x16x32_bf16(a[f], b[n], acc[f][n], 0, 0, 0);
    __syncthreads();  // all ds_reads done before next stage overwrites
  }

  // epilogue: D layout col=lane&15, row=4*(lane>>4)+reg (m89-verified)
  const int rg = (lane >> 4) * 4;
  const int cl = lane & 15;
#pragma unroll
  for (int mi = 0; mi < 4; ++mi)
#pragma unroll
    for (int n = 0; n < 4; ++n) {
      const int mg = bm * 128 + wm * 64 + mi * 16 + rg;
      const int og = bn * 128 + wn * 64 + n * 16 + cl;
#pragma unroll
      for (int r = 0; r < 4; ++r) {
        float v = acc[mi][n][r];
        size_t idx = (size_t)(mg + r) * ldc + og;
        if (EPI == 0) {
          ((u16*)outp)[idx] = f2bf(v);
        } else if (EPI == 1) {
          ((float*)outp)[idx] = resid[idx] + v + bias[og];
        } else if (EPI == 2) {
          ((u16*)outp)[idx] = f2bf(fmaxf(v + bias[og], 0.f));
        } else {
          ((float*)outp)[idx] = ((float*)outp)[idx] + v + bias[og];
        }
      }
    }
}

// ---------------- Attention: one block per (region, head); 4 waves x 64 q-rows ----------------
__device__ __forceinline__ int swz(int row, int col) {
  return row * 64 + (col ^ ((row & 7) << 3));
}

__global__ __launch_bounds__(256) void k_attn(const u16* __restrict__ qkv,
                                              u16* __restrict__ attn) {
  __shared__ u16 Ks[64 * 64];
  __shared__ u16 Vt[64 * 64];
  __shared__ u16 Pl[4 * 64 * 64];
  const int t = threadIdx.x, lane = t & 63, w = t >> 6;
  const int region = blockIdx.x >> 3;
  const int h = blockIdx.x & 7;
  const size_t n0 = (size_t)region * CC;
  const int qb = w * 64;
  const int rl = lane & 15;
  const int kg = (lane >> 4) * 8;
  u16* Pw = Pl + w * 4096;

  bf16x8 aq[4][2];
#pragma unroll
  for (int f = 0; f < 4; ++f)
#pragma unroll
    for (int ks = 0; ks < 2; ++ks)
      aq[f][ks] = *(const bf16x8*)&qkv[(n0 + qb + f * 16 + rl) * 1536 + h * 64 + ks * 32 + kg];

  f32x4 oacc[4][4] = {};
  float mrun[4][4], lrun[4][4];
#pragma unroll
  for (int i = 0; i < 4; ++i)
#pragma unroll
    for (int j = 0; j < 4; ++j) { mrun[i][j] = -1e30f; lrun[i][j] = 0.f; }

  const int sr = t >> 2;
  const int sc = (t & 3) * 16;
  for (int kt = 0; kt < 4; ++kt) {
    if (kt) __syncthreads();
    {
      const u16* kp = &qkv[(n0 + kt * 64 + sr) * 1536 + 512 + h * 64 + sc];
      bf16x8 k0 = *(const bf16x8*)kp;
      bf16x8 k1 = *(const bf16x8*)(kp + 8);
      *(bf16x8*)&Ks[swz(sr, sc)] = k0;
      *(bf16x8*)&Ks[swz(sr, sc + 8)] = k1;
      const u16* vp = &qkv[(n0 + kt * 64 + sr) * 1536 + 1024 + h * 64 + sc];
      bf16x8 v0 = *(const bf16x8*)vp;
      bf16x8 v1 = *(const bf16x8*)(vp + 8);
#pragma unroll
      for (int i = 0; i < 8; ++i) Vt[swz(sc + i, sr)] = ((u16*)&v0)[i];
#pragma unroll
      for (int i = 0; i < 8; ++i) Vt[swz(sc + 8 + i, sr)] = ((u16*)&v1)[i];
    }
    __syncthreads();
    f32x4 sacc[4][4] = {};
#pragma unroll
    for (int ks = 0; ks < 2; ++ks) {
      bf16x8 bk[4];
#pragma unroll
      for (int f = 0; f < 4; ++f) bk[f] = *(const bf16x8*)&Ks[swz(f * 16 + rl, ks * 32 + kg)];
#pragma unroll
      for (int i = 0; i < 4; ++i)
#pragma unroll
        for (int j = 0; j < 4; ++j)
          sacc[i][j] = __builtin_amdgcn_mfma_f32_16x16x32_bf16(aq[i][ks], bk[j], sacc[i][j], 0, 0, 0);
    }
#pragma unroll
    for (int i = 0; i < 4; ++i)
#pragma unroll
      for (int j = 0; j < 4; ++j)
#pragma unroll
        for (int r = 0; r < 4; ++r) sacc[i][j][r] *= 0.125f;
#pragma unroll
    for (int i = 0; i < 4; ++i) {
#pragma unroll
      for (int r = 0; r < 4; ++r) {
        float v = fmaxf(fmaxf(sacc[i][0][r], sacc[i][1][r]), fmaxf(sacc[i][2][r], sacc[i][3][r]));
#pragma unroll
        for (int m = 1; m < 16; m <<= 1) v = fmaxf(v, __shfl_xor(v, m));
        float mnew = fmaxf(mrun[i][r], v);
        float fac = __expf(mrun[i][r] - mnew);
        mrun[i][r] = mnew;
        float ps = 0.f;
#pragma unroll
        for (int fn = 0; fn < 4; ++fn) {
          float p = __expf(sacc[i][fn][r] - mnew);
          sacc[i][fn][r] = p;
          ps += p;
        }
#pragma unroll
        for (int m = 1; m < 16; m <<= 1) ps += __shfl_xor(ps, m);
        lrun[i][r] = lrun[i][r] * fac + ps;
#pragma unroll
        for (int fd = 0; fd < 4; ++fd) oacc[i][fd][r] *= fac;
      }
#pragma unroll
      for (int fn = 0; fn < 4; ++fn)
#pragma unroll
        for (int r = 0; r < 4; ++r)
          Pw[swz(i * 16 + (lane >> 4) * 4 + r, fn * 16 + rl)] = f2bf(sacc[i][fn][r]);
    }
#pragma unroll
    for (int ks = 0; ks < 2; ++ks) {
      bf16x8 ap[4], bv[4];
#pragma unroll
      for (int f = 0; f < 4; ++f) ap[f] = *(const bf16x8*)&Pw[swz(f * 16 + rl, ks * 32 + kg)];
#pragma unroll
      for (int f = 0; f < 4; ++f) bv[f] = *(const bf16x8*)&Vt[swz(f * 16 + rl, ks * 32 + kg)];
#pragma unroll
      for (int i = 0; i < 4; ++i)
#pragma unroll
        for (int j = 0; j < 4; ++j)
          oacc[i][j] = __builtin_amdgcn_mfma_f32_16x16x32_bf16(ap[i], bv[j], oacc[i][j], 0, 0, 0);
    }
  }
#pragma unroll
  for (int i = 0; i < 4; ++i)
#pragma unroll
    for (int fd = 0; fd < 4; ++fd)
#pragma unroll
      for (int r = 0; r < 4; ++r) {
        float v = oacc[i][fd][r] / lrun[i][r];
        attn[(n0 + qb + i * 16 + (lane >> 4) * 4 + r) * 512 + h * 64 + fd * 16 + rl] = f2bf(v);
      }
}

// ---------------- host launch ----------------
extern "C" void kernel_launch(void* const* d_in, const int* in_sizes, int n_in,
                              void* d_out, int out_size, void* d_ws, size_t ws_size,
                              hipStream_t stream) {
  (void)in_sizes; (void)n_in; (void)out_size; (void)ws_size;
  const float* x   = (const float*)d_in[0];
  const float* Wq  = (const float*)d_in[1];
  const float* Wk  = (const float*)d_in[2];
  const float* Wv  = (const float*)d_in[3];
  const float* Wo  = (const float*)d_in[4];
  const float* bo  = (const float*)d_in[5];
  const float* W1  = (const float*)d_in[6];
  const float* b1  = (const float*)d_in[7];
  const float* W2  = (const float*)d_in[8];
  const float* b2  = (const float*)d_in[9];
  const float* g1  = (const float*)d_in[10];
  const float* be1 = (const float*)d_in[11];
  const float* g2  = (const float*)d_in[12];
  const float* be2 = (const float*)d_in[13];
  float* out = (float*)d_out;

  char* ws = (char*)d_ws;
  u16* wqkv = (u16*)(ws + 0);          // [1536][512] bf16
  u16* wo   = (u16*)(ws + 1572864);    // [512][512]
  u16* w1   = (u16*)(ws + 2097152);    // [2048][512]
  u16* w2   = (u16*)(ws + 4194304);    // [512][2048]
  u16* regA = (u16*)(ws + 6291456);    // [N][512] bf16: h / attn / h2
  u16* regB = (u16*)(ws + 39845888);   // [N][1536] qkv, then [N][2048] ff

  k_convall<<<1024, 256, 0, stream>>>(Wq, Wk, Wv, Wo, W1, W2, wqkv, wo, w1, w2);
  k_ln<<<NTOK / 4, 256, 0, stream>>>(x, g1, be1, regA);
  // QKV: [32768x512] x [1536x512]^T -> [N][1536]; 256 bm x 12 bn
  k_gemm<0><<<dim3(256 * 12), 256, 0, stream>>>(regA, wqkv, 512, nullptr, nullptr, regB, 1536, 12);
  k_attn<<<dim3(4 * 32 * 8), 256, 0, stream>>>(regB, regA);
  // proj + bias + residual(x) -> out (f32); 256 x 4
  k_gemm<1><<<dim3(256 * 4), 256, 0, stream>>>(regA, wo, 512, bo, x, out, 512, 4);
  k_ln<<<NTOK / 4, 256, 0, stream>>>(out, g2, be2, regA);
  // FFN1: relu(h2 * w1^T + b1) -> [N][2048]; 256 x 16
  k_gemm<2><<<dim3(256 * 16), 256, 0, stream>>>(regA, w1, 512, b1, nullptr, regB, 2048, 16);
  // FFN2: out += ff * w2^T + b2; 256 x 4
  k_gemm<3><<<dim3(256 * 4), 256, 0, stream>>>(regB, w2, 2048, b2, nullptr, out, 512, 4);
}

// Round 14
// 422.966 us; speedup vs baseline: 1.2316x; 1.2316x over previous
//
#include <hip/hip_runtime.h>
#include <cstdint>
#include <cstddef>

// EEGFormer block on MI355X. N=32768 tokens, L=512, H=8 heads of D=64, C=256 region.
#define NTOK 32768
#define LDIM 512
#define HN 8
#define HD 64
#define CC 256
#define FFD 2048

typedef __bf16 bf16x8 __attribute__((ext_vector_type(8)));
typedef float f32x4 __attribute__((ext_vector_type(4)));
typedef unsigned short u16;
typedef unsigned int u32;

__device__ __forceinline__ u16 f2bf(float f) {
  u32 u = __float_as_uint(f);
  u32 r = (u + 0x7fffu + ((u >> 16) & 1u)) >> 16;  // RNE
  return (u16)r;
}

__device__ __forceinline__ void gload_lds16(const void* g, void* l) {
  __builtin_amdgcn_global_load_lds(
      (__attribute__((address_space(1))) void*)(void*)g,
      (__attribute__((address_space(3))) void*)l, 16, 0, 0);
}

// ---------------- f32 -> bf16 convert (all weights, one launch) ----------------
__global__ void k_convall(const float* __restrict__ Wq, const float* __restrict__ Wk,
                          const float* __restrict__ Wv, const float* __restrict__ Wo,
                          const float* __restrict__ W1, const float* __restrict__ W2,
                          u16* __restrict__ wqkv, u16* __restrict__ wo,
                          u16* __restrict__ w1, u16* __restrict__ w2) {
  const int NW = 262144;            // 512*512
  const int MW = 1048576;           // 2048*512
  const int TOT = 4 * NW + 2 * MW;  // 3145728
  int i = blockIdx.x * blockDim.x + threadIdx.x;
  const int st = gridDim.x * blockDim.x;
  for (; i < TOT; i += st) {
    if (i < NW) wqkv[i] = f2bf(Wq[i]);
    else if (i < 2 * NW) wqkv[i] = f2bf(Wk[i - NW]);
    else if (i < 3 * NW) wqkv[i] = f2bf(Wv[i - 2 * NW]);
    else if (i < 4 * NW) wo[i - 3 * NW] = f2bf(Wo[i - 3 * NW]);
    else if (i < 4 * NW + MW) w1[i - 4 * NW] = f2bf(W1[i - 4 * NW]);
    else w2[i - 4 * NW - MW] = f2bf(W2[i - 4 * NW - MW]);
  }
}

// ---------------- LayerNorm (f32 in -> bf16 out), 1 wave per row ----------------
__global__ __launch_bounds__(256) void k_ln(const float* __restrict__ x,
                                            const float* __restrict__ gam,
                                            const float* __restrict__ bet,
                                            u16* __restrict__ out) {
  const int row = blockIdx.x * 4 + (threadIdx.x >> 6);
  const int lane = threadIdx.x & 63;
  const float4* xr = (const float4*)(x + (size_t)row * LDIM);
  float4 a = xr[lane * 2], b = xr[lane * 2 + 1];
  float s = a.x + a.y + a.z + a.w + b.x + b.y + b.z + b.w;
  float q = a.x * a.x + a.y * a.y + a.z * a.z + a.w * a.w +
            b.x * b.x + b.y * b.y + b.z * b.z + b.w * b.w;
#pragma unroll
  for (int m = 1; m < 64; m <<= 1) { s += __shfl_xor(s, m); q += __shfl_xor(q, m); }
  const float mean = s * (1.f / LDIM);
  const float rs = rsqrtf(q * (1.f / LDIM) - mean * mean + 1e-5f);
  const int c0 = lane * 8;
  const float4* g4 = (const float4*)(gam + c0);
  const float4* b4 = (const float4*)(bet + c0);
  float4 ga = g4[0], gb = g4[1], ba = b4[0], bb = b4[1];
  float vin[8] = {a.x, a.y, a.z, a.w, b.x, b.y, b.z, b.w};
  float vg[8]  = {ga.x, ga.y, ga.z, ga.w, gb.x, gb.y, gb.z, gb.w};
  float vb[8]  = {ba.x, ba.y, ba.z, ba.w, bb.x, bb.y, bb.z, bb.w};
  u16 o[8];
#pragma unroll
  for (int i = 0; i < 8; ++i) o[i] = f2bf((vin[i] - mean) * rs * vg[i] + vb[i]);
  *(bf16x8*)(out + (size_t)row * LDIM + c0) = *(bf16x8*)o;
}

// ---------------- 128Mx256N GEMM, BK=32, depth-2 pipeline: C = A[M,K]*Bw[N,K]^T ----------------
// 8 waves (2Mx4N, wave-tile 64x64), TRIPLE-buffered 72KB LDS, launch_bounds(512,4)
// -> 2 blocks/CU. THE FIX (R12 post-mortem): previous loops issued stage(T+1) and
// drained it with VM0 in the SAME iteration -> ~900cy latency naked on every tile.
// Now: stage(T+2) issued at iter T; vmcnt(3) drains stage(T+1) (issued a full
// iteration earlier -> latency hidden). Invariant: entering iter T, exactly
// stage(T+1)'s 3 loads outstanding. WAR on buf[(T+2)%3]=buf[(T-1)%3] protected by
// barrier(T-1) + per-wave lgkm-before-MFMA. Tail: VM0 when no T+2.
// bn-major ordering: consecutive co-XCD blocks share the A-panel (L2 reuse, R12:
// FETCH 300->106MB). Swizzle: 16B chunk c of row r at slot c^((r>>1)&3) on
// pre-swizzled global source AND ds_read (involution; 0 conflicts since R3).
// EPI: 0 bf16 store; 1 +bias+resid(f32)->f32; 2 relu(+bias)->bf16; 3 f32 out += acc+bias

__device__ __forceinline__ void stage_tile(const u16* __restrict__ Ag,
                                           const u16* __restrict__ Bg, int K, int k0,
                                           u16* __restrict__ SA, u16* __restrict__ SB,
                                           int t) {
  // A: 128x32 = 512 16B-chunks, 1 per thread
  {
    const int r = t >> 2;
    const int c = ((t & 3) ^ ((r >> 1) & 3)) << 3;
    gload_lds16(Ag + (size_t)r * K + k0 + c, SA + ((t & ~63) << 3));
  }
  // B: 256x32 = 1024 chunks, 2 per thread
#pragma unroll
  for (int i = 0; i < 2; ++i) {
    const int p = i * 512 + t;
    const int r = p >> 2;
    const int c = ((p & 3) ^ ((r >> 1) & 3)) << 3;
    gload_lds16(Bg + (size_t)r * K + k0 + c, SB + ((i * 512 + (t & ~63)) << 3));
  }
}

__device__ __forceinline__ bf16x8 ldsfrag32(const u16* __restrict__ s, int R, int kq) {
  return *(const bf16x8*)(s + R * 32 + ((kq ^ ((R >> 1) & 3)) << 3));
}

#define VM3 asm volatile("s_waitcnt vmcnt(3)" ::: "memory")
#define VM0 asm volatile("s_waitcnt vmcnt(0)" ::: "memory")
#define BARRIER asm volatile("s_barrier" ::: "memory")

template <int EPI>
__global__ __launch_bounds__(512, 4) void k_gemm(const u16* __restrict__ A,
                                                 const u16* __restrict__ Bw, int K,
                                                 const float* __restrict__ bias,
                                                 const float* __restrict__ resid,
                                                 void* __restrict__ outp, int ldc,
                                                 int bnN) {
  extern __shared__ u16 lds_g[];
  // elems: A bufs at {0,4096,8192} (128x32 each); B bufs at 12288+{0,8192,16384}
  // (256x32 each). Total 36864 u16 = 72KB.
  const int t = threadIdx.x;
  const int lane = t & 63;
  const int w = t >> 6;
  const int wm = w >> 2, wn = w & 3;  // 2Mx4N waves, wave tile 64x64
  const int rl = lane & 15;
  const int kq = lane >> 4;  // 16B chunk within 32-K row
  // XCD-chunked block swizzle (grid %8==0); bn-major: consecutive co-XCD
  // sids share bm (the A-panel) and span bn.
  const int nwg = gridDim.x;
  const int cpx = nwg >> 3;
  const int id = blockIdx.x;
  const int sid = (id & 7) * cpx + (id >> 3);
  const int bn = sid % bnN, bm = sid / bnN;

  const u16* Ag = A + (size_t)bm * 128 * K;
  const u16* Bg = Bw + (size_t)bn * 256 * K;

  f32x4 acc[4][4] = {};

  // prologue: stage tiles 0 and 1 (depth-2), drain tile 0
  stage_tile(Ag, Bg, K, 0, lds_g + 0, lds_g + 12288, t);
  stage_tile(Ag, Bg, K, 32, lds_g + 4096, lds_g + 12288 + 8192, t);
  VM3;
  BARRIER;

  const int NT = K >> 5;
  for (int T = 0; T < NT; ++T) {
    const int cur = T % 3;
    // issue stage(T+2) first: maximum slack before its drain at iter T+1
    if (T + 2 < NT) {
      const int nx2 = (T + 2) % 3;
      stage_tile(Ag, Bg, K, (T + 2) << 5, lds_g + nx2 * 4096,
                 lds_g + 12288 + nx2 * 8192, t);
    }
    const u16* sA = lds_g + cur * 4096;
    const u16* sB = lds_g + 12288 + cur * 8192;
    bf16x8 a[4], b[4];
#pragma unroll
    for (int f = 0; f < 4; ++f) a[f] = ldsfrag32(sA, wm * 64 + f * 16 + rl, kq);
#pragma unroll
    for (int n = 0; n < 4; ++n) b[n] = ldsfrag32(sB, wn * 64 + n * 16 + rl, kq);
#pragma unroll
    for (int f = 0; f < 4; ++f)
#pragma unroll
      for (int n = 0; n < 4; ++n)
        acc[f][n] = __builtin_amdgcn_mfma_f32_16x16x32_bf16(a[f], b[n], acc[f][n], 0, 0, 0);
    // drain tile T+1 (issued at iter T-1 -> latency already hidden)
    if (T + 2 < NT) { VM3; } else if (T + 1 < NT) { VM0; }
    BARRIER;
  }

  // epilogue: D layout col=lane&15, row=4*(lane>>4)+reg (m89-verified)
  const int rg = (lane >> 4) * 4;
  const int cl = lane & 15;
#pragma unroll
  for (int mi = 0; mi < 4; ++mi)
#pragma unroll
    for (int n = 0; n < 4; ++n) {
      const int mg = bm * 128 + wm * 64 + mi * 16 + rg;
      const int og = bn * 256 + wn * 64 + n * 16 + cl;
#pragma unroll
      for (int r = 0; r < 4; ++r) {
        float v = acc[mi][n][r];
        size_t idx = (size_t)(mg + r) * ldc + og;
        if (EPI == 0) {
          ((u16*)outp)[idx] = f2bf(v);
        } else if (EPI == 1) {
          ((float*)outp)[idx] = resid[idx] + v + bias[og];
        } else if (EPI == 2) {
          ((u16*)outp)[idx] = f2bf(fmaxf(v + bias[og], 0.f));
        } else {
          ((float*)outp)[idx] = ((float*)outp)[idx] + v + bias[og];
        }
      }
    }
}

// ---------------- Attention: one block per (region, head); 4 waves x 64 q-rows ----------------
__device__ __forceinline__ int swz(int row, int col) {
  return row * 64 + (col ^ ((row & 7) << 3));
}

__global__ __launch_bounds__(256) void k_attn(const u16* __restrict__ qkv,
                                              u16* __restrict__ attn) {
  __shared__ u16 Ks[64 * 64];
  __shared__ u16 Vt[64 * 64];
  __shared__ u16 Pl[4 * 64 * 64];
  const int t = threadIdx.x, lane = t & 63, w = t >> 6;
  const int region = blockIdx.x >> 3;
  const int h = blockIdx.x & 7;
  const size_t n0 = (size_t)region * CC;
  const int qb = w * 64;
  const int rl = lane & 15;
  const int kg = (lane >> 4) * 8;
  u16* Pw = Pl + w * 4096;

  bf16x8 aq[4][2];
#pragma unroll
  for (int f = 0; f < 4; ++f)
#pragma unroll
    for (int ks = 0; ks < 2; ++ks)
      aq[f][ks] = *(const bf16x8*)&qkv[(n0 + qb + f * 16 + rl) * 1536 + h * 64 + ks * 32 + kg];

  f32x4 oacc[4][4] = {};
  float mrun[4][4], lrun[4][4];
#pragma unroll
  for (int i = 0; i < 4; ++i)
#pragma unroll
    for (int j = 0; j < 4; ++j) { mrun[i][j] = -1e30f; lrun[i][j] = 0.f; }

  const int sr = t >> 2;
  const int sc = (t & 3) * 16;
  for (int kt = 0; kt < 4; ++kt) {
    if (kt) __syncthreads();
    {
      const u16* kp = &qkv[(n0 + kt * 64 + sr) * 1536 + 512 + h * 64 + sc];
      bf16x8 k0 = *(const bf16x8*)kp;
      bf16x8 k1 = *(const bf16x8*)(kp + 8);
      *(bf16x8*)&Ks[swz(sr, sc)] = k0;
      *(bf16x8*)&Ks[swz(sr, sc + 8)] = k1;
      const u16* vp = &qkv[(n0 + kt * 64 + sr) * 1536 + 1024 + h * 64 + sc];
      bf16x8 v0 = *(const bf16x8*)vp;
      bf16x8 v1 = *(const bf16x8*)(vp + 8);
#pragma unroll
      for (int i = 0; i < 8; ++i) Vt[swz(sc + i, sr)] = ((u16*)&v0)[i];
#pragma unroll
      for (int i = 0; i < 8; ++i) Vt[swz(sc + 8 + i, sr)] = ((u16*)&v1)[i];
    }
    __syncthreads();
    f32x4 sacc[4][4] = {};
#pragma unroll
    for (int ks = 0; ks < 2; ++ks) {
      bf16x8 bk[4];
#pragma unroll
      for (int f = 0; f < 4; ++f) bk[f] = *(const bf16x8*)&Ks[swz(f * 16 + rl, ks * 32 + kg)];
#pragma unroll
      for (int i = 0; i < 4; ++i)
#pragma unroll
        for (int j = 0; j < 4; ++j)
          sacc[i][j] = __builtin_amdgcn_mfma_f32_16x16x32_bf16(aq[i][ks], bk[j], sacc[i][j], 0, 0, 0);
    }
#pragma unroll
    for (int i = 0; i < 4; ++i)
#pragma unroll
      for (int j = 0; j < 4; ++j)
#pragma unroll
        for (int r = 0; r < 4; ++r) sacc[i][j][r] *= 0.125f;
#pragma unroll
    for (int i = 0; i < 4; ++i) {
#pragma unroll
      for (int r = 0; r < 4; ++r) {
        float v = fmaxf(fmaxf(sacc[i][0][r], sacc[i][1][r]), fmaxf(sacc[i][2][r], sacc[i][3][r]));
#pragma unroll
        for (int m = 1; m < 16; m <<= 1) v = fmaxf(v, __shfl_xor(v, m));
        float mnew = fmaxf(mrun[i][r], v);
        float fac = __expf(mrun[i][r] - mnew);
        mrun[i][r] = mnew;
        float ps = 0.f;
#pragma unroll
        for (int fn = 0; fn < 4; ++fn) {
          float p = __expf(sacc[i][fn][r] - mnew);
          sacc[i][fn][r] = p;
          ps += p;
        }
#pragma unroll
        for (int m = 1; m < 16; m <<= 1) ps += __shfl_xor(ps, m);
        lrun[i][r] = lrun[i][r] * fac + ps;
#pragma unroll
        for (int fd = 0; fd < 4; ++fd) oacc[i][fd][r] *= fac;
      }
#pragma unroll
      for (int fn = 0; fn < 4; ++fn)
#pragma unroll
        for (int r = 0; r < 4; ++r)
          Pw[swz(i * 16 + (lane >> 4) * 4 + r, fn * 16 + rl)] = f2bf(sacc[i][fn][r]);
    }
#pragma unroll
    for (int ks = 0; ks < 2; ++ks) {
      bf16x8 ap[4], bv[4];
#pragma unroll
      for (int f = 0; f < 4; ++f) ap[f] = *(const bf16x8*)&Pw[swz(f * 16 + rl, ks * 32 + kg)];
#pragma unroll
      for (int f = 0; f < 4; ++f) bv[f] = *(const bf16x8*)&Vt[swz(f * 16 + rl, ks * 32 + kg)];
#pragma unroll
      for (int i = 0; i < 4; ++i)
#pragma unroll
        for (int j = 0; j < 4; ++j)
          oacc[i][j] = __builtin_amdgcn_mfma_f32_16x16x32_bf16(ap[i], bv[j], oacc[i][j], 0, 0, 0);
    }
  }
#pragma unroll
  for (int i = 0; i < 4; ++i)
#pragma unroll
    for (int fd = 0; fd < 4; ++fd)
#pragma unroll
      for (int r = 0; r < 4; ++r) {
        float v = oacc[i][fd][r] / lrun[i][r];
        attn[(n0 + qb + i * 16 + (lane >> 4) * 4 + r) * 512 + h * 64 + fd * 16 + rl] = f2bf(v);
      }
}

// ---------------- host launch ----------------
extern "C" void kernel_launch(void* const* d_in, const int* in_sizes, int n_in,
                              void* d_out, int out_size, void* d_ws, size_t ws_size,
                              hipStream_t stream) {
  (void)in_sizes; (void)n_in; (void)out_size; (void)ws_size;
  const float* x   = (const float*)d_in[0];
  const float* Wq  = (const float*)d_in[1];
  const float* Wk  = (const float*)d_in[2];
  const float* Wv  = (const float*)d_in[3];
  const float* Wo  = (const float*)d_in[4];
  const float* bo  = (const float*)d_in[5];
  const float* W1  = (const float*)d_in[6];
  const float* b1  = (const float*)d_in[7];
  const float* W2  = (const float*)d_in[8];
  const float* b2  = (const float*)d_in[9];
  const float* g1  = (const float*)d_in[10];
  const float* be1 = (const float*)d_in[11];
  const float* g2  = (const float*)d_in[12];
  const float* be2 = (const float*)d_in[13];
  float* out = (float*)d_out;

  char* ws = (char*)d_ws;
  u16* wqkv = (u16*)(ws + 0);          // [1536][512] bf16
  u16* wo   = (u16*)(ws + 1572864);    // [512][512]
  u16* w1   = (u16*)(ws + 2097152);    // [2048][512]
  u16* w2   = (u16*)(ws + 4194304);    // [512][2048]
  u16* regA = (u16*)(ws + 6291456);    // [N][512] bf16: h / attn / h2
  u16* regB = (u16*)(ws + 39845888);   // [N][1536] qkv, then [N][2048] ff

  const size_t LDSB = 73728;  // 72KB dynamic LDS (3-buffer pipeline, 2 blocks/CU)

  k_convall<<<1024, 256, 0, stream>>>(Wq, Wk, Wv, Wo, W1, W2, wqkv, wo, w1, w2);
  k_ln<<<NTOK / 4, 256, 0, stream>>>(x, g1, be1, regA);
  // QKV: [32768x512] x [1536x512]^T -> [N][1536]; 256 bm x 6 bn
  k_gemm<0><<<dim3(256 * 6), 512, LDSB, stream>>>(regA, wqkv, 512, nullptr, nullptr, regB, 1536, 6);
  k_attn<<<dim3(4 * 32 * 8), 256, 0, stream>>>(regB, regA);
  // proj + bias + residual(x) -> out (f32); 256 x 2
  k_gemm<1><<<dim3(256 * 2), 512, LDSB, stream>>>(regA, wo, 512, bo, x, out, 512, 2);
  k_ln<<<NTOK / 4, 256, 0, stream>>>(out, g2, be2, regA);
  // FFN1: relu(h2 * w1^T + b1) -> [N][2048]; 256 x 8
  k_gemm<2><<<dim3(256 * 8), 512, LDSB, stream>>>(regA, w1, 512, b1, nullptr, regB, 2048, 8);
  // FFN2: out += ff * w2^T + b2; 256 x 2
  k_gemm<3><<<dim3(256 * 2), 512, LDSB, stream>>>(regB, w2, 2048, b2, nullptr, out, 512, 2);
}